// Round 1
// baseline (2272.805 us; speedup 1.0000x reference)
//
#include <hip/hip_runtime.h>

typedef unsigned short u16;
typedef unsigned int u32;
typedef unsigned long long u64;
typedef __attribute__((ext_vector_type(8))) short short8;
typedef __attribute__((ext_vector_type(4))) float float4_t;
typedef __attribute__((ext_vector_type(2))) u32 u32x2;

__device__ __forceinline__ float bf2f(u16 v) {
    union { u32 u; float f; } x; x.u = ((u32)v) << 16; return x.f;
}
__device__ __forceinline__ u16 f2bf(float f) {
    union { float f; u32 u; } x; x.f = f;
    u32 r = x.u + 0x7FFFu + ((x.u >> 16) & 1u);
    return (u16)(r >> 16);
}
__device__ __forceinline__ float bitsf(u32 u) {
    union { u32 u; float f; } x; x.u = u; return x.f;
}
// pack two floats' (biased-rounded) bf16 into one u32: [hi:lo]
__device__ __forceinline__ u32 pk2bf(float hi, float lo) {
    union { float f; u32 u; } a, b; a.f = hi; b.f = lo;
    return __builtin_amdgcn_perm(a.u + 0x8000u, b.u + 0x8000u, 0x07060302u);
}
#define LOG2E 1.44269504088896340736f
__device__ __forceinline__ float tanh_(float x) {  // 1 - 2/(1+e^{2x})
    float t = __builtin_amdgcn_exp2f(2.f * LOG2E * x);
    return 1.f - 2.f * __builtin_amdgcn_rcpf(1.f + t);
}

__device__ __forceinline__ float4_t mfma16(short8 a, short8 b, float4_t c) {
    return __builtin_amdgcn_mfma_f32_16x16x32_bf16(a, b, c, 0, 0, 0);
}

// fragment loaders: 8 contiguous K-elements starting at p
__device__ __forceinline__ short8 ldfrag(const u16* p) { return *(const short8*)p; }
__device__ __forceinline__ short8 ldfrag(const float* p) {
    float4_t a = *(const float4_t*)p;
    float4_t b = *(const float4_t*)(p + 4);
    short8 r;
#pragma unroll
    for (int j = 0; j < 4; ++j) { r[j] = (short)f2bf(a[j]); r[4 + j] = (short)f2bf(b[j]); }
    return r;
}
__device__ __forceinline__ short8 ldfrag_scaled(const float* p, float s) {
    float4_t a = *(const float4_t*)p;
    float4_t b = *(const float4_t*)(p + 4);
    short8 r;
#pragma unroll
    for (int j = 0; j < 4; ++j) { r[j] = (short)f2bf(a[j] * s); r[4 + j] = (short)f2bf(b[j] * s); }
    return r;
}

// ---------------------------------------------------------------------------
// gemm_ih: Xih[M,512](bf16) = scale(col) * (A[M,128] @ W[512,128]^T + b1 + b2)
// Gate pre-activations are pre-scaled so the LSTM gates skip the exp2-argument
// multiply: cols [0,256)+[384,512) (i,f,o) get -log2e; cols [256,384) (g) +2log2e.
// ---------------------------------------------------------------------------
template<typename AT>
__global__ __launch_bounds__(256) void gemm_ih(
    const AT* __restrict__ A, const float* __restrict__ W,
    const float* __restrict__ b1, const float* __restrict__ b2,
    u16* __restrict__ C, int M)
{
    const int P = 512;
    const int lane = threadIdx.x & 63;
    const int w    = threadIdx.x >> 6;
    const int l15  = lane & 15;
    const int quad = lane >> 4;
    const int rowbase = blockIdx.x * 64;
    const int colbase = blockIdx.y * 128 + w * 32;

    short8 af[4][4];
#pragma unroll
    for (int mb = 0; mb < 4; ++mb) {
        int row = rowbase + mb * 16 + l15;
        if (row >= M) row = M - 1;
        const AT* ap = A + (size_t)row * 128 + quad * 8;
#pragma unroll
        for (int kb = 0; kb < 4; ++kb) af[mb][kb] = ldfrag(ap + kb * 32);
    }
    short8 bfr[2][4];
#pragma unroll
    for (int nb = 0; nb < 2; ++nb) {
        int col = colbase + nb * 16 + l15;
        const float* wp = W + (size_t)col * 128 + quad * 8;
#pragma unroll
        for (int kb = 0; kb < 4; ++kb) bfr[nb][kb] = ldfrag(wp + kb * 32);
    }
    const float4_t z4 = {0.f, 0.f, 0.f, 0.f};
    float bias[2], scl[2];
#pragma unroll
    for (int nb = 0; nb < 2; ++nb) {
        int col = colbase + nb * 16 + l15;
        bias[nb] = b1[col] + b2[col];
        scl[nb] = (col >= 256 && col < 384) ? (2.f * LOG2E) : (-LOG2E);
    }
#pragma unroll
    for (int mb = 0; mb < 4; ++mb)
#pragma unroll
        for (int nb = 0; nb < 2; ++nb) {
            float4_t a = z4;
#pragma unroll
            for (int kb = 0; kb < 4; ++kb) a = mfma16(af[mb][kb], bfr[nb][kb], a);
#pragma unroll
            for (int r = 0; r < 4; ++r) {
                int row = rowbase + mb * 16 + quad * 4 + r;
                int col = colbase + nb * 16 + l15;
                if (row < M) C[(size_t)row * P + col] = f2bf((a[r] + bias[nb]) * scl[nb]);
            }
        }
}

// ---------------------------------------------------------------------------
// gemm_out: P[M,128](f32) = A1@W1^T + A2@W2^T + bias ; per-col sum/sumsq atomics
// ---------------------------------------------------------------------------
template<typename T>
__device__ __forceinline__ void accum_gemm(
    const T* __restrict__ A, const float* __restrict__ W,
    float4_t (&acc)[4][2], int M, int rowbase, int colbase, int l15, int quad)
{
    short8 af[4][4];
#pragma unroll
    for (int mb = 0; mb < 4; ++mb) {
        int row = rowbase + mb * 16 + l15;
        if (row >= M) row = M - 1;
        const T* ap = A + (size_t)row * 128 + quad * 8;
#pragma unroll
        for (int kb = 0; kb < 4; ++kb) af[mb][kb] = ldfrag(ap + kb * 32);
    }
    short8 bfr[2][4];
#pragma unroll
    for (int nb = 0; nb < 2; ++nb) {
        int col = colbase + nb * 16 + l15;
        const float* wp = W + (size_t)col * 128 + quad * 8;
#pragma unroll
        for (int kb = 0; kb < 4; ++kb) bfr[nb][kb] = ldfrag(wp + kb * 32);
    }
#pragma unroll
    for (int mb = 0; mb < 4; ++mb)
#pragma unroll
        for (int nb = 0; nb < 2; ++nb)
#pragma unroll
            for (int kb = 0; kb < 4; ++kb)
                acc[mb][nb] = mfma16(af[mb][kb], bfr[nb][kb], acc[mb][nb]);
}

template<typename AT2>
__global__ __launch_bounds__(256) void gemm_out(
    const u16* __restrict__ A1, const float* __restrict__ W1,
    const AT2* __restrict__ A2, const float* __restrict__ W2,
    const float* __restrict__ bias, float* __restrict__ C,
    float* __restrict__ stats, int M)
{
    const int P = 128;
    const int lane = threadIdx.x & 63;
    const int w    = threadIdx.x >> 6;
    const int l15  = lane & 15;
    const int quad = lane >> 4;
    const int rowbase = blockIdx.x * 64;
    const int colbase = w * 32;

    float4_t acc[4][2];
    const float4_t z4 = {0.f, 0.f, 0.f, 0.f};
#pragma unroll
    for (int mb = 0; mb < 4; ++mb)
#pragma unroll
        for (int nb = 0; nb < 2; ++nb) acc[mb][nb] = z4;

    accum_gemm(A1, W1, acc, M, rowbase, colbase, l15, quad);
    accum_gemm(A2, W2, acc, M, rowbase, colbase, l15, quad);

    float s[2] = {0.f, 0.f}, sq[2] = {0.f, 0.f};
#pragma unroll
    for (int nb = 0; nb < 2; ++nb) {
        int col = colbase + nb * 16 + l15;
        float bb = bias[col];
#pragma unroll
        for (int mb = 0; mb < 4; ++mb)
#pragma unroll
            for (int r = 0; r < 4; ++r) {
                int row = rowbase + mb * 16 + quad * 4 + r;
                if (row < M) {
                    float v = acc[mb][nb][r] + bb;
                    C[(size_t)row * P + col] = v;
                    s[nb] += v; sq[nb] += v * v;
                }
            }
    }
#pragma unroll
    for (int nb = 0; nb < 2; ++nb) {
        float t1 = s[nb], t2 = sq[nb];
        t1 += __shfl_xor(t1, 16); t1 += __shfl_xor(t1, 32);
        t2 += __shfl_xor(t2, 16); t2 += __shfl_xor(t2, 32);
        int col = colbase + nb * 16 + l15;
        if (quad == 0) atomicAdd(&stats[col], t1);
        if (quad == 1) atomicAdd(&stats[P + col], t2);
    }
}

// ---------------------------------------------------------------------------
// Persistent LSTM aggregator, transposed formulation: z^T = Whh*h^T + Xih^T.
// 512 thr (8 waves), 64 nodes/block, 16 steps. Wave w owns dim-slice
// [16w,16w+16) of each gate. C-layout: lane holds dims quad*4+r of node l15.
// Gathered Xih rows are loaded DIRECTLY in accumulator layout (8B/lane/gate,
// no identity-MFMA, no wave-pair duplicate fetch). Gate pre-activations arrive
// pre-scaled (-log2e / +2log2e) so gates are rcp(1+exp2(z)).
// hbuf: 256B stride + XOR chunk swizzle (chunk ^= row&7) — write b64 4-way
// conflict -> 2-way (free), reads stay 2-way.
// ---------------------------------------------------------------------------
__global__ __launch_bounds__(512, 4) void lstm_kernel(
    const u16* __restrict__ Xih,   // [N,512] bf16, pre-scaled gate order i,f,g,o
    const int* __restrict__ nbr,   // [N,16]
    const float* __restrict__ Whh, // [512,128] f32 (unscaled; scaled at frag load)
    u16* __restrict__ Hout,        // [N,128] bf16
    int N)
{
    __shared__ u16 hbuf[2][64][128];
    __shared__ int nbrs[16][72];   // [step][node], padded
    const int tid  = threadIdx.x;
    const int lane = tid & 63;
    const int w    = tid >> 6;           // wave 0..7
    const int l15  = lane & 15;
    const int quad = lane >> 4;
    const int base = blockIdx.x * 64;

    // Whh A-fragments (register-resident): rows = output dims 128g+16w+l15,
    // pre-scaled per gate (g==2 is the tanh gate).
    short8 whA[4][4];
#pragma unroll
    for (int g = 0; g < 4; ++g) {
        int row = 128 * g + 16 * w + l15;
        float s = (g == 2) ? (2.f * LOG2E) : (-LOG2E);
        const float* wp = Whh + (size_t)row * 128 + quad * 8;
#pragma unroll
        for (int kb = 0; kb < 4; ++kb) whA[g][kb] = ldfrag_scaled(wp + kb * 32, s);
    }
    // zero both h buffers; stage neighbor indices (coalesced global reads)
    u32* hz = (u32*)&hbuf[0][0][0];
    for (int i = tid; i < 2 * 64 * 128 / 2; i += 512) hz[i] = 0u;
    for (int i = tid; i < 64 * 16; i += 512) {
        int node = base + (i >> 4);
        if (node >= N) node = N - 1;
        nbrs[i & 15][i >> 4] = nbr[(size_t)node * 16 + (i & 15)];
    }
    __syncthreads();

    // gather layout: lane (l15,quad) of wave w needs Xih[node][128g+16w+4q .. +3]
    // = one 8B load per gate, exactly the accumulator fragment this lane owns.
    const int xoff = 16 * w + 4 * quad;      // u16 units within each 128-col gate block

    // prefetch step 0 gather
    u32x2 xfu[4][4];                          // [nb][g]
#pragma unroll
    for (int nb = 0; nb < 4; ++nb) {
        int node = nbrs[0][l15 + 16 * nb];
        const u16* xp = Xih + (size_t)node * 512 + xoff;
#pragma unroll
        for (int g = 0; g < 4; ++g) xfu[nb][g] = *(const u32x2*)(xp + 128 * g);
    }

    const float4_t z4 = {0.f, 0.f, 0.f, 0.f};
    float4_t c[4];
#pragma unroll
    for (int nb = 0; nb < 4; ++nb) c[nb] = z4;
    u64 pklast[4];

    for (int t = 0; t < 16; ++t) {
        const int p = t & 1;
#pragma unroll
        for (int nb = 0; nb < 4; ++nb) {
            const int row = l15 + 16 * nb;
            // h(t-1) B-frags from LDS (XOR-swizzled chunks)
            const char* hrow = (const char*)&hbuf[p][row][0];
            short8 hb[4];
#pragma unroll
            for (int kb = 0; kb < 4; ++kb) {
                int ch = (quad + 4 * kb) ^ (row & 7);
                hb[kb] = *(const short8*)(hrow + (ch << 4));
            }
            // init accumulators directly from gathered Xih (consumes xfu[nb])
            float4_t z[4];
#pragma unroll
            for (int g = 0; g < 4; ++g) {
                u32 w0 = xfu[nb][g][0], w1 = xfu[nb][g][1];
                z[g][0] = bitsf(w0 << 16); z[g][1] = bitsf(w0 & 0xFFFF0000u);
                z[g][2] = bitsf(w1 << 16); z[g][3] = bitsf(w1 & 0xFFFF0000u);
            }
            // prefetch next step's gather into xfu[nb] (after unpack reads)
            if (t < 15) {
                int node = nbrs[t + 1][l15 + 16 * nb];
                const u16* xp = Xih + (size_t)node * 512 + xoff;
#pragma unroll
                for (int g = 0; g < 4; ++g) xfu[nb][g] = *(const u32x2*)(xp + 128 * g);
            }
            // recurrent GEMM
#pragma unroll
            for (int g = 0; g < 4; ++g)
#pragma unroll
                for (int kb = 0; kb < 4; ++kb)
                    z[g] = mfma16(whA[g][kb], hb[kb], z[g]);
            // gates: z pre-scaled so i,f,o = rcp(1+exp2(z)), g = 1-2*rcp(1+exp2(z))
            float4_t hv;
#pragma unroll
            for (int r = 0; r < 4; ++r) {
                float i_ = __builtin_amdgcn_rcpf(1.f + __builtin_amdgcn_exp2f(z[0][r]));
                float f_ = __builtin_amdgcn_rcpf(1.f + __builtin_amdgcn_exp2f(z[1][r]));
                float g_ = 1.f - 2.f * __builtin_amdgcn_rcpf(1.f + __builtin_amdgcn_exp2f(z[2][r]));
                float o_ = __builtin_amdgcn_rcpf(1.f + __builtin_amdgcn_exp2f(z[3][r]));
                float cc = f_ * c[nb][r] + i_ * g_;
                c[nb][r] = cc;
                hv[r] = o_ * tanh_(cc);
            }
            // packed h write: 4 contiguous bf16 dims -> one ds_write_b64 (swizzled)
            u64 pkd = ((u64)pk2bf(hv[3], hv[2]) << 32) | pk2bf(hv[1], hv[0]);
            pklast[nb] = pkd;
            int ch = (2 * w + (quad >> 1)) ^ (row & 7);
            int sw = (ch << 4) | ((quad & 1) << 3);
            *(u64*)((char*)&hbuf[1 - p][row][0] + sw) = pkd;
        }
        __syncthreads();
    }
#pragma unroll
    for (int nb = 0; nb < 4; ++nb) {
        int row = base + l15 + 16 * nb;
        if (row < N)
            *(u64*)(Hout + (size_t)row * 128 + 16 * w + 4 * quad) = pklast[nb];
    }
}

// ---------------------------------------------------------------------------
__global__ void zero_stats(float* s) { s[threadIdx.x] = 0.f; }   // 256 thr

__global__ void bn_prep(float* stats, const float* __restrict__ gamma,
                        const float* __restrict__ beta, float invN)
{
    int cidx = threadIdx.x;   // 0..127
    float s = stats[cidx], sq = stats[128 + cidx];
    float mu = s * invN;
    float var = sq * invN - mu * mu;
    float sc = gamma[cidx] * rsqrtf(var + 1e-5f);
    stats[256 + cidx] = sc;
    stats[384 + cidx] = beta[cidx] - mu * sc;
}

template<typename OT>
__global__ __launch_bounds__(256) void bn_apply(
    const float* __restrict__ X, const float* __restrict__ stats,
    OT* __restrict__ Y, int M, int relu)
{
    int gid = blockIdx.x * 256 + threadIdx.x;
    int row = gid >> 4;
    int cs  = (gid & 15) * 8;
    if (row >= M) return;
    float4_t a = *(const float4_t*)(X + (size_t)row * 128 + cs);
    float4_t b = *(const float4_t*)(X + (size_t)row * 128 + cs + 4);
    float v[8];
#pragma unroll
    for (int j = 0; j < 8; ++j) {
        float x = (j < 4) ? a[j] : b[j - 4];
        float t = x * stats[256 + cs + j] + stats[384 + cs + j];
        v[j] = relu ? fmaxf(t, 0.f) : t;
    }
    if constexpr (sizeof(OT) == 2) {
        short8 ov;
#pragma unroll
        for (int j = 0; j < 8; ++j) ov[j] = (short)f2bf(v[j]);
        *(short8*)((u16*)Y + (size_t)row * 128 + cs) = ov;
    } else {
        float4_t o1, o2;
#pragma unroll
        for (int j = 0; j < 4; ++j) { o1[j] = v[j]; o2[j] = v[4 + j]; }
        *(float4_t*)((float*)Y + (size_t)row * 128 + cs) = o1;
        *(float4_t*)((float*)Y + (size_t)row * 128 + cs + 4) = o2;
    }
}

// ---------------------------------------------------------------------------
extern "C" void kernel_launch(void* const* d_in, const int* in_sizes, int n_in,
                              void* d_out, int out_size, void* d_ws, size_t ws_size,
                              hipStream_t stream)
{
    const float* in_feat = (const float*)d_in[0];
    const int*   nbr     = (const int*)d_in[1];
    const float* Wih1 = (const float*)d_in[2];
    const float* Whh1 = (const float*)d_in[3];
    const float* bih1 = (const float*)d_in[4];
    const float* bhh1 = (const float*)d_in[5];
    const float* Wself1  = (const float*)d_in[6];
    const float* bself1  = (const float*)d_in[7];
    const float* Wneigh1 = (const float*)d_in[8];
    const float* gamma1  = (const float*)d_in[9];
    const float* beta1   = (const float*)d_in[10];
    const float* Wih2 = (const float*)d_in[11];
    const float* Whh2 = (const float*)d_in[12];
    const float* bih2 = (const float*)d_in[13];
    const float* bhh2 = (const float*)d_in[14];
    const float* Wself2  = (const float*)d_in[15];
    const float* bself2  = (const float*)d_in[16];
    const float* Wneigh2 = (const float*)d_in[17];
    const float* gamma2  = (const float*)d_in[18];
    const float* beta2   = (const float*)d_in[19];

    const int N = in_sizes[0] / 128;

    char* ws = (char*)d_ws;
    u16*   Xih   = (u16*)ws;                       // [N,512] bf16 (aliases Pbuf)
    float* Pbuf  = (float*)ws;                     // [N,128] f32
    u16*   hn    = (u16*)(ws + (size_t)N * 1024);  // [N,128] bf16
    float* stats = (float*)(ws + (size_t)N * 1024 + (size_t)N * 256);
    u16*   hcur  = (u16*)d_out;                    // bf16 scratch inside d_out

    const int nblk = (N + 63) / 64;
    const float invN = 1.0f / (float)N;
    const int bnblk = (N * 16 + 255) / 256;

    // ---------------- layer 1 ----------------
    zero_stats<<<dim3(1), dim3(256), 0, stream>>>(stats);
    gemm_ih<float><<<dim3(nblk, 4), dim3(256), 0, stream>>>(in_feat, Wih1, bih1, bhh1, Xih, N);
    lstm_kernel<<<dim3(nblk), dim3(512), 0, stream>>>(Xih, nbr, Whh1, hn, N);
    gemm_out<float><<<dim3(nblk, 1), dim3(256), 0, stream>>>(hn, Wneigh1, in_feat, Wself1,
                                                             bself1, Pbuf, stats, N);
    bn_prep<<<dim3(1), dim3(128), 0, stream>>>(stats, gamma1, beta1, invN);
    bn_apply<u16><<<dim3(bnblk), dim3(256), 0, stream>>>(Pbuf, stats, hcur, N, 1);

    // ---------------- layer 2 ----------------
    zero_stats<<<dim3(1), dim3(256), 0, stream>>>(stats);
    gemm_ih<u16><<<dim3(nblk, 4), dim3(256), 0, stream>>>(hcur, Wih2, bih2, bhh2, Xih, N);
    lstm_kernel<<<dim3(nblk), dim3(512), 0, stream>>>(Xih, nbr, Whh2, hn, N);
    gemm_out<u16><<<dim3(nblk, 1), dim3(256), 0, stream>>>(hn, Wneigh2, hcur, Wself2,
                                                           bself2, Pbuf, stats, N);
    bn_prep<<<dim3(1), dim3(128), 0, stream>>>(stats, gamma2, beta2, invN);
    bn_apply<float><<<dim3(bnblk), dim3(256), 0, stream>>>(Pbuf, stats, (float*)d_out, N, 0);
}

// Round 2
// 1711.426 us; speedup vs baseline: 1.3280x; 1.3280x over previous
//
#include <hip/hip_runtime.h>

typedef unsigned short u16;
typedef unsigned int u32;
typedef unsigned long long u64;
typedef __attribute__((ext_vector_type(8))) short short8;
typedef __attribute__((ext_vector_type(4))) float float4_t;
typedef __attribute__((ext_vector_type(2))) u32 u32x2;

__device__ __forceinline__ float bf2f(u16 v) {
    union { u32 u; float f; } x; x.u = ((u32)v) << 16; return x.f;
}
__device__ __forceinline__ u16 f2bf(float f) {
    union { float f; u32 u; } x; x.f = f;
    u32 r = x.u + 0x7FFFu + ((x.u >> 16) & 1u);
    return (u16)(r >> 16);
}
__device__ __forceinline__ float bitsf(u32 u) {
    union { u32 u; float f; } x; x.u = u; return x.f;
}
// pack two floats' (biased-rounded) bf16 into one u32: [hi:lo]
__device__ __forceinline__ u32 pk2bf(float hi, float lo) {
    union { float f; u32 u; } a, b; a.f = hi; b.f = lo;
    return __builtin_amdgcn_perm(a.u + 0x8000u, b.u + 0x8000u, 0x07060302u);
}
#define LOG2E 1.44269504088896340736f
__device__ __forceinline__ float tanh_(float x) {  // 1 - 2/(1+e^{2x})
    float t = __builtin_amdgcn_exp2f(2.f * LOG2E * x);
    return 1.f - 2.f * __builtin_amdgcn_rcpf(1.f + t);
}

__device__ __forceinline__ float4_t mfma16(short8 a, short8 b, float4_t c) {
    return __builtin_amdgcn_mfma_f32_16x16x32_bf16(a, b, c, 0, 0, 0);
}

// fragment loaders: 8 contiguous K-elements starting at p
__device__ __forceinline__ short8 ldfrag(const u16* p) { return *(const short8*)p; }
__device__ __forceinline__ short8 ldfrag(const float* p) {
    float4_t a = *(const float4_t*)p;
    float4_t b = *(const float4_t*)(p + 4);
    short8 r;
#pragma unroll
    for (int j = 0; j < 4; ++j) { r[j] = (short)f2bf(a[j]); r[4 + j] = (short)f2bf(b[j]); }
    return r;
}
__device__ __forceinline__ short8 ldfrag_scaled(const float* p, float s) {
    float4_t a = *(const float4_t*)p;
    float4_t b = *(const float4_t*)(p + 4);
    short8 r;
#pragma unroll
    for (int j = 0; j < 4; ++j) { r[j] = (short)f2bf(a[j] * s); r[4 + j] = (short)f2bf(b[j] * s); }
    return r;
}

// ---------------------------------------------------------------------------
// gemm_ih: Xih[M,512](bf16) = scale(col) * (A[M,128] @ W[512,128]^T + b1 + b2)
// Gate pre-activations are pre-scaled so the LSTM gates skip the exp2-argument
// multiply: cols [0,256)+[384,512) (i,f,o) get -log2e; cols [256,384) (g) +2log2e.
// ---------------------------------------------------------------------------
template<typename AT>
__global__ __launch_bounds__(256) void gemm_ih(
    const AT* __restrict__ A, const float* __restrict__ W,
    const float* __restrict__ b1, const float* __restrict__ b2,
    u16* __restrict__ C, int M)
{
    const int P = 512;
    const int lane = threadIdx.x & 63;
    const int w    = threadIdx.x >> 6;
    const int l15  = lane & 15;
    const int quad = lane >> 4;
    const int rowbase = blockIdx.x * 64;
    const int colbase = blockIdx.y * 128 + w * 32;

    short8 af[4][4];
#pragma unroll
    for (int mb = 0; mb < 4; ++mb) {
        int row = rowbase + mb * 16 + l15;
        if (row >= M) row = M - 1;
        const AT* ap = A + (size_t)row * 128 + quad * 8;
#pragma unroll
        for (int kb = 0; kb < 4; ++kb) af[mb][kb] = ldfrag(ap + kb * 32);
    }
    short8 bfr[2][4];
#pragma unroll
    for (int nb = 0; nb < 2; ++nb) {
        int col = colbase + nb * 16 + l15;
        const float* wp = W + (size_t)col * 128 + quad * 8;
#pragma unroll
        for (int kb = 0; kb < 4; ++kb) bfr[nb][kb] = ldfrag(wp + kb * 32);
    }
    const float4_t z4 = {0.f, 0.f, 0.f, 0.f};
    float bias[2], scl[2];
#pragma unroll
    for (int nb = 0; nb < 2; ++nb) {
        int col = colbase + nb * 16 + l15;
        bias[nb] = b1[col] + b2[col];
        scl[nb] = (col >= 256 && col < 384) ? (2.f * LOG2E) : (-LOG2E);
    }
#pragma unroll
    for (int mb = 0; mb < 4; ++mb)
#pragma unroll
        for (int nb = 0; nb < 2; ++nb) {
            float4_t a = z4;
#pragma unroll
            for (int kb = 0; kb < 4; ++kb) a = mfma16(af[mb][kb], bfr[nb][kb], a);
#pragma unroll
            for (int r = 0; r < 4; ++r) {
                int row = rowbase + mb * 16 + quad * 4 + r;
                int col = colbase + nb * 16 + l15;
                if (row < M) C[(size_t)row * P + col] = f2bf((a[r] + bias[nb]) * scl[nb]);
            }
        }
}

// ---------------------------------------------------------------------------
// gemm_out: P[M,128](f32) = A1@W1^T + A2@W2^T + bias ; per-col sum/sumsq atomics
// ---------------------------------------------------------------------------
template<typename T>
__device__ __forceinline__ void accum_gemm(
    const T* __restrict__ A, const float* __restrict__ W,
    float4_t (&acc)[4][2], int M, int rowbase, int colbase, int l15, int quad)
{
    short8 af[4][4];
#pragma unroll
    for (int mb = 0; mb < 4; ++mb) {
        int row = rowbase + mb * 16 + l15;
        if (row >= M) row = M - 1;
        const T* ap = A + (size_t)row * 128 + quad * 8;
#pragma unroll
        for (int kb = 0; kb < 4; ++kb) af[mb][kb] = ldfrag(ap + kb * 32);
    }
    short8 bfr[2][4];
#pragma unroll
    for (int nb = 0; nb < 2; ++nb) {
        int col = colbase + nb * 16 + l15;
        const float* wp = W + (size_t)col * 128 + quad * 8;
#pragma unroll
        for (int kb = 0; kb < 4; ++kb) bfr[nb][kb] = ldfrag(wp + kb * 32);
    }
#pragma unroll
    for (int mb = 0; mb < 4; ++mb)
#pragma unroll
        for (int nb = 0; nb < 2; ++nb)
#pragma unroll
            for (int kb = 0; kb < 4; ++kb)
                acc[mb][nb] = mfma16(af[mb][kb], bfr[nb][kb], acc[mb][nb]);
}

template<typename AT2>
__global__ __launch_bounds__(256) void gemm_out(
    const u16* __restrict__ A1, const float* __restrict__ W1,
    const AT2* __restrict__ A2, const float* __restrict__ W2,
    const float* __restrict__ bias, float* __restrict__ C,
    float* __restrict__ stats, int M)
{
    const int P = 128;
    const int lane = threadIdx.x & 63;
    const int w    = threadIdx.x >> 6;
    const int l15  = lane & 15;
    const int quad = lane >> 4;
    const int rowbase = blockIdx.x * 64;
    const int colbase = w * 32;

    float4_t acc[4][2];
    const float4_t z4 = {0.f, 0.f, 0.f, 0.f};
#pragma unroll
    for (int mb = 0; mb < 4; ++mb)
#pragma unroll
        for (int nb = 0; nb < 2; ++nb) acc[mb][nb] = z4;

    accum_gemm(A1, W1, acc, M, rowbase, colbase, l15, quad);
    accum_gemm(A2, W2, acc, M, rowbase, colbase, l15, quad);

    float s[2] = {0.f, 0.f}, sq[2] = {0.f, 0.f};
#pragma unroll
    for (int nb = 0; nb < 2; ++nb) {
        int col = colbase + nb * 16 + l15;
        float bb = bias[col];
#pragma unroll
        for (int mb = 0; mb < 4; ++mb)
#pragma unroll
            for (int r = 0; r < 4; ++r) {
                int row = rowbase + mb * 16 + quad * 4 + r;
                if (row < M) {
                    float v = acc[mb][nb][r] + bb;
                    C[(size_t)row * P + col] = v;
                    s[nb] += v; sq[nb] += v * v;
                }
            }
    }
#pragma unroll
    for (int nb = 0; nb < 2; ++nb) {
        float t1 = s[nb], t2 = sq[nb];
        t1 += __shfl_xor(t1, 16); t1 += __shfl_xor(t1, 32);
        t2 += __shfl_xor(t2, 16); t2 += __shfl_xor(t2, 32);
        int col = colbase + nb * 16 + l15;
        if (quad == 0) atomicAdd(&stats[col], t1);
        if (quad == 1) atomicAdd(&stats[P + col], t2);
    }
}

// ---------------------------------------------------------------------------
// Persistent LSTM aggregator, transposed formulation: z^T = Whh*h^T + Xih^T.
// 512 thr (8 waves), 64 nodes/block, 16 steps. Wave w owns dim-slice
// [16w,16w+16) of each gate. C-layout: lane holds dims quad*4+r of node l15.
// Gathered Xih rows are loaded DIRECTLY in accumulator layout (8B/lane/gate,
// no identity-MFMA, no wave-pair duplicate fetch). Gate pre-activations arrive
// pre-scaled (-log2e / +2log2e) so gates are rcp(1+exp2(z)).
// __launch_bounds__(512,2): the 2nd arg behaves as min BLOCKS/CU — (512,4)
// forced a 64-VGPR budget and spilled ~1.7 GB/dispatch to scratch (round-1
// regression). 2 blocks/CU = 128-VGPR budget = no spill.
// ---------------------------------------------------------------------------
__global__ __launch_bounds__(512, 2) void lstm_kernel(
    const u16* __restrict__ Xih,   // [N,512] bf16, pre-scaled gate order i,f,g,o
    const int* __restrict__ nbr,   // [N,16]
    const float* __restrict__ Whh, // [512,128] f32 (unscaled; scaled at frag load)
    u16* __restrict__ Hout,        // [N,128] bf16
    int N)
{
    __shared__ u16 hbuf[2][64][128];
    __shared__ int nbrs[16][72];   // [step][node], padded
    const int tid  = threadIdx.x;
    const int lane = tid & 63;
    const int w    = tid >> 6;           // wave 0..7
    const int l15  = lane & 15;
    const int quad = lane >> 4;
    const int base = blockIdx.x * 64;

    // Whh A-fragments (register-resident): rows = output dims 128g+16w+l15,
    // pre-scaled per gate (g==2 is the tanh gate).
    short8 whA[4][4];
#pragma unroll
    for (int g = 0; g < 4; ++g) {
        int row = 128 * g + 16 * w + l15;
        float s = (g == 2) ? (2.f * LOG2E) : (-LOG2E);
        const float* wp = Whh + (size_t)row * 128 + quad * 8;
#pragma unroll
        for (int kb = 0; kb < 4; ++kb) whA[g][kb] = ldfrag_scaled(wp + kb * 32, s);
    }
    // zero both h buffers; stage neighbor indices (coalesced global reads)
    u32* hz = (u32*)&hbuf[0][0][0];
    for (int i = tid; i < 2 * 64 * 128 / 2; i += 512) hz[i] = 0u;
    for (int i = tid; i < 64 * 16; i += 512) {
        int node = base + (i >> 4);
        if (node >= N) node = N - 1;
        nbrs[i & 15][i >> 4] = nbr[(size_t)node * 16 + (i & 15)];
    }
    __syncthreads();

    // gather layout: lane (l15,quad) of wave w needs Xih[node][128g+16w+4q .. +3]
    // = one 8B load per gate, exactly the accumulator fragment this lane owns.
    const int xoff = 16 * w + 4 * quad;      // u16 units within each 128-col gate block

    // prefetch step 0 gather
    u32x2 xfu[4][4];                          // [nb][g]
#pragma unroll
    for (int nb = 0; nb < 4; ++nb) {
        int node = nbrs[0][l15 + 16 * nb];
        const u16* xp = Xih + (size_t)node * 512 + xoff;
#pragma unroll
        for (int g = 0; g < 4; ++g) xfu[nb][g] = *(const u32x2*)(xp + 128 * g);
    }

    const float4_t z4 = {0.f, 0.f, 0.f, 0.f};
    float4_t c[4];
#pragma unroll
    for (int nb = 0; nb < 4; ++nb) c[nb] = z4;
    u64 pklast[4];

    for (int t = 0; t < 16; ++t) {
        const int p = t & 1;
#pragma unroll
        for (int nb = 0; nb < 4; ++nb) {
            const int row = l15 + 16 * nb;
            // h(t-1) B-frags from LDS (XOR-swizzled chunks)
            const char* hrow = (const char*)&hbuf[p][row][0];
            short8 hb[4];
#pragma unroll
            for (int kb = 0; kb < 4; ++kb) {
                int ch = (quad + 4 * kb) ^ (row & 7);
                hb[kb] = *(const short8*)(hrow + (ch << 4));
            }
            // init accumulators directly from gathered Xih (consumes xfu[nb])
            float4_t z[4];
#pragma unroll
            for (int g = 0; g < 4; ++g) {
                u32 w0 = xfu[nb][g][0], w1 = xfu[nb][g][1];
                z[g][0] = bitsf(w0 << 16); z[g][1] = bitsf(w0 & 0xFFFF0000u);
                z[g][2] = bitsf(w1 << 16); z[g][3] = bitsf(w1 & 0xFFFF0000u);
            }
            // prefetch next step's gather into xfu[nb] (after unpack reads)
            if (t < 15) {
                int node = nbrs[t + 1][l15 + 16 * nb];
                const u16* xp = Xih + (size_t)node * 512 + xoff;
#pragma unroll
                for (int g = 0; g < 4; ++g) xfu[nb][g] = *(const u32x2*)(xp + 128 * g);
            }
            // recurrent GEMM
#pragma unroll
            for (int g = 0; g < 4; ++g)
#pragma unroll
                for (int kb = 0; kb < 4; ++kb)
                    z[g] = mfma16(whA[g][kb], hb[kb], z[g]);
            // gates: z pre-scaled so i,f,o = rcp(1+exp2(z)), g = 1-2*rcp(1+exp2(z))
            float4_t hv;
#pragma unroll
            for (int r = 0; r < 4; ++r) {
                float i_ = __builtin_amdgcn_rcpf(1.f + __builtin_amdgcn_exp2f(z[0][r]));
                float f_ = __builtin_amdgcn_rcpf(1.f + __builtin_amdgcn_exp2f(z[1][r]));
                float g_ = 1.f - 2.f * __builtin_amdgcn_rcpf(1.f + __builtin_amdgcn_exp2f(z[2][r]));
                float o_ = __builtin_amdgcn_rcpf(1.f + __builtin_amdgcn_exp2f(z[3][r]));
                float cc = f_ * c[nb][r] + i_ * g_;
                c[nb][r] = cc;
                hv[r] = o_ * tanh_(cc);
            }
            // packed h write: 4 contiguous bf16 dims -> one ds_write_b64 (swizzled)
            u64 pkd = ((u64)pk2bf(hv[3], hv[2]) << 32) | pk2bf(hv[1], hv[0]);
            pklast[nb] = pkd;
            int ch = (2 * w + (quad >> 1)) ^ (row & 7);
            int sw = (ch << 4) | ((quad & 1) << 3);
            *(u64*)((char*)&hbuf[1 - p][row][0] + sw) = pkd;
        }
        __syncthreads();
    }
#pragma unroll
    for (int nb = 0; nb < 4; ++nb) {
        int row = base + l15 + 16 * nb;
        if (row < N)
            *(u64*)(Hout + (size_t)row * 128 + 16 * w + 4 * quad) = pklast[nb];
    }
}

// ---------------------------------------------------------------------------
__global__ void zero_stats(float* s) { s[threadIdx.x] = 0.f; }   // 256 thr

__global__ void bn_prep(float* stats, const float* __restrict__ gamma,
                        const float* __restrict__ beta, float invN)
{
    int cidx = threadIdx.x;   // 0..127
    float s = stats[cidx], sq = stats[128 + cidx];
    float mu = s * invN;
    float var = sq * invN - mu * mu;
    float sc = gamma[cidx] * rsqrtf(var + 1e-5f);
    stats[256 + cidx] = sc;
    stats[384 + cidx] = beta[cidx] - mu * sc;
}

template<typename OT>
__global__ __launch_bounds__(256) void bn_apply(
    const float* __restrict__ X, const float* __restrict__ stats,
    OT* __restrict__ Y, int M, int relu)
{
    int gid = blockIdx.x * 256 + threadIdx.x;
    int row = gid >> 4;
    int cs  = (gid & 15) * 8;
    if (row >= M) return;
    float4_t a = *(const float4_t*)(X + (size_t)row * 128 + cs);
    float4_t b = *(const float4_t*)(X + (size_t)row * 128 + cs + 4);
    float v[8];
#pragma unroll
    for (int j = 0; j < 8; ++j) {
        float x = (j < 4) ? a[j] : b[j - 4];
        float t = x * stats[256 + cs + j] + stats[384 + cs + j];
        v[j] = relu ? fmaxf(t, 0.f) : t;
    }
    if constexpr (sizeof(OT) == 2) {
        short8 ov;
#pragma unroll
        for (int j = 0; j < 8; ++j) ov[j] = (short)f2bf(v[j]);
        *(short8*)((u16*)Y + (size_t)row * 128 + cs) = ov;
    } else {
        float4_t o1, o2;
#pragma unroll
        for (int j = 0; j < 4; ++j) { o1[j] = v[j]; o2[j] = v[4 + j]; }
        *(float4_t*)((float*)Y + (size_t)row * 128 + cs) = o1;
        *(float4_t*)((float*)Y + (size_t)row * 128 + cs + 4) = o2;
    }
}

// ---------------------------------------------------------------------------
extern "C" void kernel_launch(void* const* d_in, const int* in_sizes, int n_in,
                              void* d_out, int out_size, void* d_ws, size_t ws_size,
                              hipStream_t stream)
{
    const float* in_feat = (const float*)d_in[0];
    const int*   nbr     = (const int*)d_in[1];
    const float* Wih1 = (const float*)d_in[2];
    const float* Whh1 = (const float*)d_in[3];
    const float* bih1 = (const float*)d_in[4];
    const float* bhh1 = (const float*)d_in[5];
    const float* Wself1  = (const float*)d_in[6];
    const float* bself1  = (const float*)d_in[7];
    const float* Wneigh1 = (const float*)d_in[8];
    const float* gamma1  = (const float*)d_in[9];
    const float* beta1   = (const float*)d_in[10];
    const float* Wih2 = (const float*)d_in[11];
    const float* Whh2 = (const float*)d_in[12];
    const float* bih2 = (const float*)d_in[13];
    const float* bhh2 = (const float*)d_in[14];
    const float* Wself2  = (const float*)d_in[15];
    const float* bself2  = (const float*)d_in[16];
    const float* Wneigh2 = (const float*)d_in[17];
    const float* gamma2  = (const float*)d_in[18];
    const float* beta2   = (const float*)d_in[19];

    const int N = in_sizes[0] / 128;

    char* ws = (char*)d_ws;
    u16*   Xih   = (u16*)ws;                       // [N,512] bf16 (aliases Pbuf)
    float* Pbuf  = (float*)ws;                     // [N,128] f32
    u16*   hn    = (u16*)(ws + (size_t)N * 1024);  // [N,128] bf16
    float* stats = (float*)(ws + (size_t)N * 1024 + (size_t)N * 256);
    u16*   hcur  = (u16*)d_out;                    // bf16 scratch inside d_out

    const int nblk = (N + 63) / 64;
    const float invN = 1.0f / (float)N;
    const int bnblk = (N * 16 + 255) / 256;

    // ---------------- layer 1 ----------------
    zero_stats<<<dim3(1), dim3(256), 0, stream>>>(stats);
    gemm_ih<float><<<dim3(nblk, 4), dim3(256), 0, stream>>>(in_feat, Wih1, bih1, bhh1, Xih, N);
    lstm_kernel<<<dim3(nblk), dim3(512), 0, stream>>>(Xih, nbr, Whh1, hn, N);
    gemm_out<float><<<dim3(nblk, 1), dim3(256), 0, stream>>>(hn, Wneigh1, in_feat, Wself1,
                                                             bself1, Pbuf, stats, N);
    bn_prep<<<dim3(1), dim3(128), 0, stream>>>(stats, gamma1, beta1, invN);
    bn_apply<u16><<<dim3(bnblk), dim3(256), 0, stream>>>(Pbuf, stats, hcur, N, 1);

    // ---------------- layer 2 ----------------
    zero_stats<<<dim3(1), dim3(256), 0, stream>>>(stats);
    gemm_ih<u16><<<dim3(nblk, 4), dim3(256), 0, stream>>>(hcur, Wih2, bih2, bhh2, Xih, N);
    lstm_kernel<<<dim3(nblk), dim3(512), 0, stream>>>(Xih, nbr, Whh2, hn, N);
    gemm_out<u16><<<dim3(nblk, 1), dim3(256), 0, stream>>>(hn, Wneigh2, hcur, Wself2,
                                                           bself2, Pbuf, stats, N);
    bn_prep<<<dim3(1), dim3(128), 0, stream>>>(stats, gamma2, beta2, invN);
    bn_apply<float><<<dim3(bnblk), dim3(256), 0, stream>>>(Pbuf, stats, (float*)d_out, N, 0);
}

// Round 4
// 1538.259 us; speedup vs baseline: 1.4775x; 1.1126x over previous
//
#include <hip/hip_runtime.h>

typedef unsigned short u16;
typedef unsigned int u32;
typedef unsigned long long u64;
typedef __attribute__((ext_vector_type(8))) short short8;
typedef __attribute__((ext_vector_type(4))) float float4_t;
typedef __attribute__((ext_vector_type(2))) u32 u32x2;

__device__ __forceinline__ u16 f2bf(float f) {
    union { float f; u32 u; } x; x.f = f;
    u32 r = x.u + 0x7FFFu + ((x.u >> 16) & 1u);
    return (u16)(r >> 16);
}
__device__ __forceinline__ float bitsf(u32 u) {
    union { u32 u; float f; } x; x.u = u; return x.f;
}
// pack two floats' (biased-rounded) bf16 into one u32: [hi:lo]
__device__ __forceinline__ u32 pk2bf(float hi, float lo) {
    union { float f; u32 u; } a, b; a.f = hi; b.f = lo;
    return __builtin_amdgcn_perm(a.u + 0x8000u, b.u + 0x8000u, 0x07060302u);
}
#define LOG2E 1.44269504088896340736f
__device__ __forceinline__ float tanh_(float x) {  // 1 - 2/(1+e^{2x})
    float t = __builtin_amdgcn_exp2f(2.f * LOG2E * x);
    return 1.f - 2.f * __builtin_amdgcn_rcpf(1.f + t);
}

__device__ __forceinline__ float4_t mfma16(short8 a, short8 b, float4_t c) {
    return __builtin_amdgcn_mfma_f32_16x16x32_bf16(a, b, c, 0, 0, 0);
}

// barrier that does NOT drain vmcnt: LDS ordering only. Gather prefetches
// stay in flight across the step boundary (compiler still inserts correct
// vmcnt waits at their consumption points).
#define LDS_BARRIER() asm volatile("s_waitcnt lgkmcnt(0)\n\ts_barrier" ::: "memory")

// fragment loaders: 8 contiguous K-elements starting at p
__device__ __forceinline__ short8 ldfrag(const u16* p) { return *(const short8*)p; }
__device__ __forceinline__ short8 ldfrag(const float* p) {
    float4_t a = *(const float4_t*)p;
    float4_t b = *(const float4_t*)(p + 4);
    short8 r;
#pragma unroll
    for (int j = 0; j < 4; ++j) { r[j] = (short)f2bf(a[j]); r[4 + j] = (short)f2bf(b[j]); }
    return r;
}
__device__ __forceinline__ short8 ldfrag_scaled(const float* p, float s) {
    float4_t a = *(const float4_t*)p;
    float4_t b = *(const float4_t*)(p + 4);
    short8 r;
#pragma unroll
    for (int j = 0; j < 4; ++j) { r[j] = (short)f2bf(a[j] * s); r[4 + j] = (short)f2bf(b[j] * s); }
    return r;
}

// ---------------------------------------------------------------------------
// gemm_ih: Xih[M,512](bf16) = scale(col) * (A[M,128] @ W[512,128]^T + b1 + b2)
// Gate pre-activations pre-scaled: i,f,o cols get -log2e; g cols +2log2e.
// Block (0,0) also zeroes stats[0..256) (replaces the zero_stats launch).
// ---------------------------------------------------------------------------
template<typename AT>
__global__ __launch_bounds__(256) void gemm_ih(
    const AT* __restrict__ A, const float* __restrict__ W,
    const float* __restrict__ b1, const float* __restrict__ b2,
    u16* __restrict__ C, float* __restrict__ stats, int M)
{
    if (blockIdx.x == 0 && blockIdx.y == 0) stats[threadIdx.x] = 0.f;
    const int P = 512;
    const int lane = threadIdx.x & 63;
    const int w    = threadIdx.x >> 6;
    const int l15  = lane & 15;
    const int quad = lane >> 4;
    const int rowbase = blockIdx.x * 64;
    const int colbase = blockIdx.y * 128 + w * 32;

    short8 af[4][4];
#pragma unroll
    for (int mb = 0; mb < 4; ++mb) {
        int row = rowbase + mb * 16 + l15;
        if (row >= M) row = M - 1;
        const AT* ap = A + (size_t)row * 128 + quad * 8;
#pragma unroll
        for (int kb = 0; kb < 4; ++kb) af[mb][kb] = ldfrag(ap + kb * 32);
    }
    short8 bfr[2][4];
#pragma unroll
    for (int nb = 0; nb < 2; ++nb) {
        int col = colbase + nb * 16 + l15;
        const float* wp = W + (size_t)col * 128 + quad * 8;
#pragma unroll
        for (int kb = 0; kb < 4; ++kb) bfr[nb][kb] = ldfrag(wp + kb * 32);
    }
    const float4_t z4 = {0.f, 0.f, 0.f, 0.f};
    float bias[2], scl[2];
#pragma unroll
    for (int nb = 0; nb < 2; ++nb) {
        int col = colbase + nb * 16 + l15;
        bias[nb] = b1[col] + b2[col];
        scl[nb] = (col >= 256 && col < 384) ? (2.f * LOG2E) : (-LOG2E);
    }
#pragma unroll
    for (int mb = 0; mb < 4; ++mb)
#pragma unroll
        for (int nb = 0; nb < 2; ++nb) {
            float4_t a = z4;
#pragma unroll
            for (int kb = 0; kb < 4; ++kb) a = mfma16(af[mb][kb], bfr[nb][kb], a);
#pragma unroll
            for (int r = 0; r < 4; ++r) {
                int row = rowbase + mb * 16 + quad * 4 + r;
                int col = colbase + nb * 16 + l15;
                if (row < M) C[(size_t)row * P + col] = f2bf((a[r] + bias[nb]) * scl[nb]);
            }
        }
}

// ---------------------------------------------------------------------------
// gemm_out: P[M,128](f32) = A1@W1^T + A2@W2^T + bias ; per-col sum/sumsq atomics
// ---------------------------------------------------------------------------
template<typename T>
__device__ __forceinline__ void accum_gemm(
    const T* __restrict__ A, const float* __restrict__ W,
    float4_t (&acc)[4][2], int M, int rowbase, int colbase, int l15, int quad)
{
    short8 af[4][4];
#pragma unroll
    for (int mb = 0; mb < 4; ++mb) {
        int row = rowbase + mb * 16 + l15;
        if (row >= M) row = M - 1;
        const T* ap = A + (size_t)row * 128 + quad * 8;
#pragma unroll
        for (int kb = 0; kb < 4; ++kb) af[mb][kb] = ldfrag(ap + kb * 32);
    }
    short8 bfr[2][4];
#pragma unroll
    for (int nb = 0; nb < 2; ++nb) {
        int col = colbase + nb * 16 + l15;
        const float* wp = W + (size_t)col * 128 + quad * 8;
#pragma unroll
        for (int kb = 0; kb < 4; ++kb) bfr[nb][kb] = ldfrag(wp + kb * 32);
    }
#pragma unroll
    for (int mb = 0; mb < 4; ++mb)
#pragma unroll
        for (int nb = 0; nb < 2; ++nb)
#pragma unroll
            for (int kb = 0; kb < 4; ++kb)
                acc[mb][nb] = mfma16(af[mb][kb], bfr[nb][kb], acc[mb][nb]);
}

template<typename AT2>
__global__ __launch_bounds__(256) void gemm_out(
    const u16* __restrict__ A1, const float* __restrict__ W1,
    const AT2* __restrict__ A2, const float* __restrict__ W2,
    const float* __restrict__ bias, float* __restrict__ C,
    float* __restrict__ stats, int M)
{
    const int P = 128;
    const int lane = threadIdx.x & 63;
    const int w    = threadIdx.x >> 6;
    const int l15  = lane & 15;
    const int quad = lane >> 4;
    const int rowbase = blockIdx.x * 64;
    const int colbase = w * 32;

    float4_t acc[4][2];
    const float4_t z4 = {0.f, 0.f, 0.f, 0.f};
#pragma unroll
    for (int mb = 0; mb < 4; ++mb)
#pragma unroll
        for (int nb = 0; nb < 2; ++nb) acc[mb][nb] = z4;

    accum_gemm(A1, W1, acc, M, rowbase, colbase, l15, quad);
    accum_gemm(A2, W2, acc, M, rowbase, colbase, l15, quad);

    float s[2] = {0.f, 0.f}, sq[2] = {0.f, 0.f};
#pragma unroll
    for (int nb = 0; nb < 2; ++nb) {
        int col = colbase + nb * 16 + l15;
        float bb = bias[col];
#pragma unroll
        for (int mb = 0; mb < 4; ++mb)
#pragma unroll
            for (int r = 0; r < 4; ++r) {
                int row = rowbase + mb * 16 + quad * 4 + r;
                if (row < M) {
                    float v = acc[mb][nb][r] + bb;
                    C[(size_t)row * P + col] = v;
                    s[nb] += v; sq[nb] += v * v;
                }
            }
    }
#pragma unroll
    for (int nb = 0; nb < 2; ++nb) {
        float t1 = s[nb], t2 = sq[nb];
        t1 += __shfl_xor(t1, 16); t1 += __shfl_xor(t1, 32);
        t2 += __shfl_xor(t2, 16); t2 += __shfl_xor(t2, 32);
        int col = colbase + nb * 16 + l15;
        if (quad == 0) atomicAdd(&stats[col], t1);
        if (quad == 1) atomicAdd(&stats[P + col], t2);
    }
}

// ---------------------------------------------------------------------------
// Persistent LSTM aggregator, transposed formulation: z^T = Whh*h^T + Xih^T.
// 512 thr (8 waves), 64 nodes/block, 16 steps. Wave w owns dim-slice
// [16w,16w+16) of each gate; lane holds dims 16w+4*quad+r of node l15+16nb.
// Per step: z init directly from gathered Xih (accumulator-layout 8B loads),
// next-step gather prefetch, recurrent MFMA (one hb frag per kb, setprio(1)
// around the cluster), gates, swizzled ds_write. LDS_BARRIER keeps gather
// prefetches in flight across the step boundary (no vmcnt(0) drain).
// ---------------------------------------------------------------------------
__global__ __launch_bounds__(512, 2) void lstm_kernel(
    const u16* __restrict__ Xih,   // [N,512] bf16, pre-scaled gate order i,f,g,o
    const int* __restrict__ nbr,   // [N,16]
    const float* __restrict__ Whh, // [512,128] f32 (unscaled; scaled at frag load)
    u16* __restrict__ Hout,        // [N,128] bf16
    int N)
{
    __shared__ u16 hbuf[2][64][128];
    __shared__ int nbrs[16][72];   // [step][node], padded
    const int tid  = threadIdx.x;
    const int lane = tid & 63;
    const int w    = tid >> 6;           // wave 0..7
    const int l15  = lane & 15;
    const int quad = lane >> 4;
    const int base = blockIdx.x * 64;

    // Whh A-fragments (register-resident): rows = output dims 128g+16w+l15,
    // pre-scaled per gate (g==2 is the tanh gate).
    short8 whA[4][4];
#pragma unroll
    for (int g = 0; g < 4; ++g) {
        int row = 128 * g + 16 * w + l15;
        float s = (g == 2) ? (2.f * LOG2E) : (-LOG2E);
        const float* wp = Whh + (size_t)row * 128 + quad * 8;
#pragma unroll
        for (int kb = 0; kb < 4; ++kb) whA[g][kb] = ldfrag_scaled(wp + kb * 32, s);
    }
    // zero both h buffers; stage neighbor indices (coalesced global reads)
    u32* hz = (u32*)&hbuf[0][0][0];
    for (int i = tid; i < 2 * 64 * 128 / 2; i += 512) hz[i] = 0u;
    for (int i = tid; i < 64 * 16; i += 512) {
        int node = base + (i >> 4);
        if (node >= N) node = N - 1;
        nbrs[i & 15][i >> 4] = nbr[(size_t)node * 16 + (i & 15)];
    }
    __syncthreads();

    // gather layout: lane (l15,quad) of wave w needs Xih[node][128g+16w+4q .. +3]
    const int xoff = 16 * w + 4 * quad;      // u16 units within each 128-col gate block

    // prefetch step 0 gather
    u32x2 xfu[4][4];                          // [nb][g]
#pragma unroll
    for (int nb = 0; nb < 4; ++nb) {
        int node = nbrs[0][l15 + 16 * nb];
        const u16* xp = Xih + (size_t)node * 512 + xoff;
#pragma unroll
        for (int g = 0; g < 4; ++g) xfu[nb][g] = *(const u32x2*)(xp + 128 * g);
    }

    const float4_t z4 = {0.f, 0.f, 0.f, 0.f};
    float4_t c[4];
#pragma unroll
    for (int nb = 0; nb < 4; ++nb) c[nb] = z4;

    for (int t = 0; t < 16; ++t) {
        const int p = t & 1;
#pragma unroll
        for (int nb = 0; nb < 4; ++nb) {
            const int row = l15 + 16 * nb;
            // init accumulators directly from gathered Xih (consumes xfu[nb])
            float4_t z[4];
#pragma unroll
            for (int g = 0; g < 4; ++g) {
                u32 w0 = xfu[nb][g][0], w1 = xfu[nb][g][1];
                z[g][0] = bitsf(w0 << 16); z[g][1] = bitsf(w0 & 0xFFFF0000u);
                z[g][2] = bitsf(w1 << 16); z[g][3] = bitsf(w1 & 0xFFFF0000u);
            }
            // prefetch next step's gather into xfu[nb] (WAR-safe: consumed above)
            if (t < 15) {
                int node = nbrs[t + 1][row];
                const u16* xp = Xih + (size_t)node * 512 + xoff;
#pragma unroll
                for (int g = 0; g < 4; ++g) xfu[nb][g] = *(const u32x2*)(xp + 128 * g);
            }
            // recurrent GEMM: one h(t-1) B-frag per kb (XOR-swizzled), 4 MFMAs
            const char* hrow = (const char*)&hbuf[p][row][0];
            __builtin_amdgcn_s_setprio(1);
#pragma unroll
            for (int kb = 0; kb < 4; ++kb) {
                int ch = (quad + 4 * kb) ^ (row & 7);
                short8 hb = *(const short8*)(hrow + (ch << 4));
#pragma unroll
                for (int g = 0; g < 4; ++g)
                    z[g] = mfma16(whA[g][kb], hb, z[g]);
            }
            __builtin_amdgcn_s_setprio(0);
            // gates: z pre-scaled so i,f,o = rcp(1+exp2(z)), g = 1-2*rcp(1+exp2(z))
            float4_t hv;
#pragma unroll
            for (int r = 0; r < 4; ++r) {
                float i_ = __builtin_amdgcn_rcpf(1.f + __builtin_amdgcn_exp2f(z[0][r]));
                float f_ = __builtin_amdgcn_rcpf(1.f + __builtin_amdgcn_exp2f(z[1][r]));
                float g_ = 1.f - 2.f * __builtin_amdgcn_rcpf(1.f + __builtin_amdgcn_exp2f(z[2][r]));
                float o_ = __builtin_amdgcn_rcpf(1.f + __builtin_amdgcn_exp2f(z[3][r]));
                float cc = f_ * c[nb][r] + i_ * g_;
                c[nb][r] = cc;
                hv[r] = o_ * tanh_(cc);
            }
            // packed h: 4 contiguous bf16 dims -> one b64 write
            u64 pkd = ((u64)pk2bf(hv[3], hv[2]) << 32) | pk2bf(hv[1], hv[0]);
            if (t < 15) {
                int ch = (2 * w + (quad >> 1)) ^ (row & 7);
                int sw = (ch << 4) | ((quad & 1) << 3);
                *(u64*)((char*)&hbuf[1 - p][row][0] + sw) = pkd;
            } else {
                int grow = base + row;
                if (grow < N)
                    *(u64*)(Hout + (size_t)grow * 128 + xoff) = pkd;
            }
        }
        if (t < 15) LDS_BARRIER();
    }
}

// ---------------------------------------------------------------------------
__global__ void bn_prep(float* stats, const float* __restrict__ gamma,
                        const float* __restrict__ beta, float invN)
{
    int cidx = threadIdx.x;   // 0..127
    float s = stats[cidx], sq = stats[128 + cidx];
    float mu = s * invN;
    float var = sq * invN - mu * mu;
    float sc = gamma[cidx] * rsqrtf(var + 1e-5f);
    stats[256 + cidx] = sc;
    stats[384 + cidx] = beta[cidx] - mu * sc;
}

template<typename OT>
__global__ __launch_bounds__(256) void bn_apply(
    const float* __restrict__ X, const float* __restrict__ stats,
    OT* __restrict__ Y, int M, int relu)
{
    int gid = blockIdx.x * 256 + threadIdx.x;
    int row = gid >> 4;
    int cs  = (gid & 15) * 8;
    if (row >= M) return;
    float4_t a = *(const float4_t*)(X + (size_t)row * 128 + cs);
    float4_t b = *(const float4_t*)(X + (size_t)row * 128 + cs + 4);
    float v[8];
#pragma unroll
    for (int j = 0; j < 8; ++j) {
        float x = (j < 4) ? a[j] : b[j - 4];
        float t = x * stats[256 + cs + j] + stats[384 + cs + j];
        v[j] = relu ? fmaxf(t, 0.f) : t;
    }
    if constexpr (sizeof(OT) == 2) {
        short8 ov;
#pragma unroll
        for (int j = 0; j < 8; ++j) ov[j] = (short)f2bf(v[j]);
        *(short8*)((u16*)Y + (size_t)row * 128 + cs) = ov;
    } else {
        float4_t o1, o2;
#pragma unroll
        for (int j = 0; j < 4; ++j) { o1[j] = v[j]; o2[j] = v[4 + j]; }
        *(float4_t*)((float*)Y + (size_t)row * 128 + cs) = o1;
        *(float4_t*)((float*)Y + (size_t)row * 128 + cs + 4) = o2;
    }
}

// ---------------------------------------------------------------------------
extern "C" void kernel_launch(void* const* d_in, const int* in_sizes, int n_in,
                              void* d_out, int out_size, void* d_ws, size_t ws_size,
                              hipStream_t stream)
{
    const float* in_feat = (const float*)d_in[0];
    const int*   nbr     = (const int*)d_in[1];
    const float* Wih1 = (const float*)d_in[2];
    const float* Whh1 = (const float*)d_in[3];
    const float* bih1 = (const float*)d_in[4];
    const float* bhh1 = (const float*)d_in[5];
    const float* Wself1  = (const float*)d_in[6];
    const float* bself1  = (const float*)d_in[7];
    const float* Wneigh1 = (const float*)d_in[8];
    const float* gamma1  = (const float*)d_in[9];
    const float* beta1   = (const float*)d_in[10];
    const float* Wih2 = (const float*)d_in[11];
    const float* Whh2 = (const float*)d_in[12];
    const float* bih2 = (const float*)d_in[13];
    const float* bhh2 = (const float*)d_in[14];
    const float* Wself2  = (const float*)d_in[15];
    const float* bself2  = (const float*)d_in[16];
    const float* Wneigh2 = (const float*)d_in[17];
    const float* gamma2  = (const float*)d_in[18];
    const float* beta2   = (const float*)d_in[19];

    const int N = in_sizes[0] / 128;

    char* ws = (char*)d_ws;
    u16*   Xih   = (u16*)ws;                       // [N,512] bf16 (aliases Pbuf)
    float* Pbuf  = (float*)ws;                     // [N,128] f32
    u16*   hn    = (u16*)(ws + (size_t)N * 1024);  // [N,128] bf16
    float* stats = (float*)(ws + (size_t)N * 1024 + (size_t)N * 256);
    u16*   hcur  = (u16*)d_out;                    // bf16 scratch inside d_out

    const int nblk = (N + 63) / 64;
    const float invN = 1.0f / (float)N;
    const int bnblk = (N * 16 + 255) / 256;

    // ---------------- layer 1 ----------------
    gemm_ih<float><<<dim3(nblk, 4), dim3(256), 0, stream>>>(in_feat, Wih1, bih1, bhh1, Xih, stats, N);
    lstm_kernel<<<dim3(nblk), dim3(512), 0, stream>>>(Xih, nbr, Whh1, hn, N);
    gemm_out<float><<<dim3(nblk, 1), dim3(256), 0, stream>>>(hn, Wneigh1, in_feat, Wself1,
                                                             bself1, Pbuf, stats, N);
    bn_prep<<<dim3(1), dim3(128), 0, stream>>>(stats, gamma1, beta1, invN);
    bn_apply<u16><<<dim3(bnblk), dim3(256), 0, stream>>>(Pbuf, stats, hcur, N, 1);

    // ---------------- layer 2 ----------------
    gemm_ih<u16><<<dim3(nblk, 4), dim3(256), 0, stream>>>(hcur, Wih2, bih2, bhh2, Xih, stats, N);
    lstm_kernel<<<dim3(nblk), dim3(512), 0, stream>>>(Xih, nbr, Whh2, hn, N);
    gemm_out<u16><<<dim3(nblk, 1), dim3(256), 0, stream>>>(hn, Wneigh2, hcur, Wself2,
                                                           bself2, Pbuf, stats, N);
    bn_prep<<<dim3(1), dim3(128), 0, stream>>>(stats, gamma2, beta2, invN);
    bn_apply<float><<<dim3(bnblk), dim3(256), 0, stream>>>(Pbuf, stats, (float*)d_out, N, 0);
}